// Round 13
// baseline (125.665 us; speedup 1.0000x reference)
//
#include <hip/hip_runtime.h>
#include <hip/hip_bf16.h>
#include <stdint.h>

// Problem constants: B=2, S=2048, D=1024, H=16, HD=64.
// ws layout (MB): 0 hid_bf | 8 wq | 10 wk | 12 wv | 14 wo | 16 q (8MB) | 24 k (8MB)
//                 | 32 vt (8MB) | 40 ctx (8MB);  out_pre(f32,16MB) aliases q+k @16MB.

typedef unsigned short ushort_t;
typedef short bf16x8 __attribute__((ext_vector_type(8)));
typedef float f32x4 __attribute__((ext_vector_type(4)));
typedef float f32x16 __attribute__((ext_vector_type(16)));
typedef unsigned short ushort8 __attribute__((ext_vector_type(8)));

#define LOG2E 1.4426950408889634f

__device__ __forceinline__ ushort_t f2b(float f) {
  uint32_t x = __builtin_bit_cast(uint32_t, f);
  return (ushort_t)((x + 0x7FFFu + ((x >> 16) & 1u)) >> 16);
}

__device__ __forceinline__ uint32_t cvt_pk_bf16(float lo, float hi) {
  uint32_t r;
  asm("v_cvt_pk_bf16_f32 %0, %1, %2" : "=v"(r) : "v"(lo), "v"(hi));
  return r;
}

// a.upper <-> b.lower halves across the 32-lane boundary
__device__ __forceinline__ void permswap(uint32_t& a, uint32_t& b) {
  asm volatile("v_permlane32_swap_b32 %0, %1" : "+v"(a), "+v"(b));
}

__device__ __forceinline__ void gload16(const void* gptr, void* ldsptr) {
  __builtin_amdgcn_global_load_lds(
      (const __attribute__((address_space(1))) uint32_t*)gptr,
      (__attribute__((address_space(3))) uint32_t*)ldsptr, 16, 0, 0);
}

// ---------------- fused cast fp32 -> bf16 (hidden + 4 weights, one launch) ---
__global__ void cast_all_kernel(const float* __restrict__ h,
                                const float* __restrict__ a, const float* __restrict__ b,
                                const float* __restrict__ c, const float* __restrict__ d2,
                                ushort_t* __restrict__ oh, ushort_t* __restrict__ oa,
                                ushort_t* __restrict__ ob, ushort_t* __restrict__ oc,
                                ushort_t* __restrict__ od) {
  const int blk = blockIdx.x;
  const float* src;
  ushort_t* dst;
  int rel;
  if (blk < 2048) { src = h; dst = oh; rel = blk; }
  else {
    const int w = (blk - 2048) >> 9;
    rel = (blk - 2048) & 511;
    src = w == 0 ? a : w == 1 ? b : w == 2 ? c : d2;
    dst = w == 0 ? oa : w == 1 ? ob : w == 2 ? oc : od;
  }
  const int i = (rel * 256 + threadIdx.x) * 8;
  const float4* s = (const float4*)(src + i);
  float4 x = s[0], y = s[1];
  ushort8 o = { f2b(x.x), f2b(x.y), f2b(x.z), f2b(x.w),
                f2b(y.x), f2b(y.y), f2b(y.z), f2b(y.w) };
  *(ushort8*)(dst + i) = o;
}

// ---------------- fused QKV projection GEMM -----------------------------------
// 256x128 tile, BK=32, 8 waves (wm=(wave>>1)*64, wn=(wave&1)*64). T4 pipeline:
// 3 LDS buffers (72KB), per step STAGE(buf[t+2]) [3 loads/thread] -> 16 MFMA/
// wave -> s_waitcnt vmcnt(3) -> raw s_barrier (never vmcnt(0) in main loop).
// vs 128^2: 2x MFMA per 1.5x staging, half the weight re-reads, half barriers.
// which = blockIdx.z: 0 -> Q (RoPE + scale), 1 -> K (RoPE), 2 -> V^T
__global__ __launch_bounds__(512) void gemm_qkv(
    const ushort_t* __restrict__ hid, const ushort_t* __restrict__ wq,
    const ushort_t* __restrict__ wk, const ushort_t* __restrict__ wv,
    const float* __restrict__ bq, const float* __restrict__ bk,
    const float* __restrict__ bv, const float* __restrict__ cosT,
    const float* __restrict__ sinT, ushort_t* __restrict__ qout,
    ushort_t* __restrict__ kout, ushort_t* __restrict__ vtout)
{
  constexpr int K = 1024;
  __shared__ uint4 SBa[3072];   // 48KB: 3 bufs x 256 rows x 4 chunks
  __shared__ uint4 SBb[1536];   // 24KB: 3 bufs x 128 rows x 4 chunks
  const int which = blockIdx.z;
  const ushort_t* A;
  const ushort_t* Bm;
  const float* bias;
  int m0, n0;
  if (which == 0)      { A = hid; Bm = wq; bias = bq; m0 = blockIdx.x * 256; n0 = blockIdx.y * 128; }
  else if (which == 1) { A = hid; Bm = wk; bias = bk; m0 = blockIdx.x * 256; n0 = blockIdx.y * 128; }
  else                 { A = wv;  Bm = hid; bias = bv;
                         m0 = (blockIdx.y & 3) * 256;
                         n0 = (blockIdx.x + (blockIdx.y >> 2) * 16) * 128; }

  const int tid = threadIdx.x;
  const int wave = tid >> 6, lane = tid & 63;
  const int d = lane & 15, g = lane >> 4;
  const int wm = (wave >> 1) * 64, wn = (wave & 1) * 64;

  const ushort_t* ag = A + (size_t)(m0 + (tid >> 2)) * K + (tid & 3) * 8;
  const ushort_t* bg = Bm + (size_t)(n0 + (tid >> 2)) * K + (tid & 3) * 8;

  f32x4 acc[4][4] = {};

#define STAGE_Q(buf, k0)                                           \
  {                                                                \
    char* da = (char*)(SBa + (buf) * 1024) + wave * 1024;          \
    char* db = (char*)(SBb + (buf) * 512) + wave * 1024;           \
    gload16(ag + (k0), da);                                        \
    gload16(ag + 128 * K + (k0), da + 8192);                       \
    gload16(bg + (k0), db);                                        \
  }

#define COMPUTE_Q(buf)                                                          \
  {                                                                             \
    bf16x8 af[4], bfr[4];                                                       \
    _Pragma("unroll") for (int i = 0; i < 4; ++i)                               \
        af[i] = __builtin_bit_cast(bf16x8,                                      \
            SBa[(buf) * 1024 + (wm + i * 16 + d) * 4 + g]);                     \
    _Pragma("unroll") for (int j = 0; j < 4; ++j)                               \
        bfr[j] = __builtin_bit_cast(bf16x8,                                     \
            SBb[(buf) * 512 + (wn + j * 16 + d) * 4 + g]);                      \
    _Pragma("unroll") for (int i = 0; i < 4; ++i)                               \
        _Pragma("unroll") for (int j = 0; j < 4; ++j)                           \
            acc[i][j] = __builtin_amdgcn_mfma_f32_16x16x32_bf16(                \
                af[i], bfr[j], acc[i][j], 0, 0, 0);                             \
  }

  STAGE_Q(0, 0);
  STAGE_Q(1, 32);
  asm volatile("s_waitcnt vmcnt(3)" ::: "memory");
  __builtin_amdgcn_s_barrier();

  int bufc = 0;
  for (int t = 0; t < 30; ++t) {
    int bufn = bufc + 2; if (bufn >= 3) bufn -= 3;
    STAGE_Q(bufn, (t + 2) * 32);
    COMPUTE_Q(bufc);
    asm volatile("s_waitcnt vmcnt(3)" ::: "memory");   // buf[t+1] complete
    __builtin_amdgcn_s_barrier();
    bufc = (bufc == 2) ? 0 : bufc + 1;
  }
  COMPUTE_Q(bufc);
  asm volatile("s_waitcnt vmcnt(0)" ::: "memory");
  __builtin_amdgcn_s_barrier();
  bufc = (bufc == 2) ? 0 : bufc + 1;
  COMPUTE_Q(bufc);
#undef STAGE_Q
#undef COMPUTE_Q

  if (which <= 1) {
    ushort_t* O = which == 0 ? qout : kout;
    const float qscale = which == 0 ? (LOG2E / 64.0f) : 1.0f;
    const int head_base = n0 + wn;
    const int h = head_base >> 6;
#pragma unroll
    for (int i = 0; i < 4; ++i) {
#pragma unroll
      for (int r = 0; r < 4; ++r) {
        const int m = m0 + wm + i * 16 + g * 4 + r;
        const int s = m & 2047, b = m >> 11;
#pragma unroll
        for (int j = 0; j < 4; ++j) {
          const int c = j * 16 + d;
          const float v0 = acc[i][j][r] + bias[head_base + c];
          const float v1 = acc[i][j ^ 2][r] + bias[head_base + (c ^ 32)];
          const float rot = (c < 32) ? -v1 : v1;
          const float vr = (v0 * cosT[s * 64 + c] + rot * sinT[s * 64 + c]) * qscale;
          O[(size_t)(((b << 4) + h) * 2048 + s) * 64 + c] = f2b(vr);
        }
      }
    }
  } else {
    ushort_t* O = vtout;
#pragma unroll
    for (int i = 0; i < 4; ++i) {
#pragma unroll
      for (int r = 0; r < 4; ++r) {
        const int fr = m0 + wm + i * 16 + g * 4 + r;
        const float bv2 = bias[fr];
        const int h = fr >> 6, dd = fr & 63;
#pragma unroll
        for (int j = 0; j < 4; ++j) {
          const int tok = n0 + wn + j * 16 + d;
          const int b = tok >> 11, s = tok & 2047;
          O[(size_t)(((b << 4) + h) * 64 + dd) * 2048 + s] = f2b(acc[i][j][r] + bv2);
        }
      }
    }
  }
}

// ---------------- Wo GEMM (bias + residual, fp32 out), 256x128 T4 pipeline ---
__global__ __launch_bounds__(512) void gemm_wo(
    const ushort_t* __restrict__ A, const ushort_t* __restrict__ B,
    const float* __restrict__ bias, const float* __restrict__ resid,
    float* __restrict__ O)
{
  constexpr int K = 1024;
  __shared__ uint4 SBa[3072];
  __shared__ uint4 SBb[1536];
  const int tid = threadIdx.x;
  const int wave = tid >> 6, lane = tid & 63;
  const int d = lane & 15, g = lane >> 4;
  const int m0 = blockIdx.x * 256, n0 = blockIdx.y * 128;
  const int wm = (wave >> 1) * 64, wn = (wave & 1) * 64;

  const ushort_t* ag = A + (size_t)(m0 + (tid >> 2)) * K + (tid & 3) * 8;
  const ushort_t* bg = B + (size_t)(n0 + (tid >> 2)) * K + (tid & 3) * 8;

  f32x4 acc[4][4] = {};

#define STAGE_W(buf, k0)                                           \
  {                                                                \
    char* da = (char*)(SBa + (buf) * 1024) + wave * 1024;          \
    char* db = (char*)(SBb + (buf) * 512) + wave * 1024;           \
    gload16(ag + (k0), da);                                        \
    gload16(ag + 128 * K + (k0), da + 8192);                       \
    gload16(bg + (k0), db);                                        \
  }

#define COMPUTE_W(buf)                                                          \
  {                                                                             \
    bf16x8 af[4], bfr[4];                                                       \
    _Pragma("unroll") for (int i = 0; i < 4; ++i)                               \
        af[i] = __builtin_bit_cast(bf16x8,                                      \
            SBa[(buf) * 1024 + (wm + i * 16 + d) * 4 + g]);                     \
    _Pragma("unroll") for (int j = 0; j < 4; ++j)                               \
        bfr[j] = __builtin_bit_cast(bf16x8,                                     \
            SBb[(buf) * 512 + (wn + j * 16 + d) * 4 + g]);                      \
    _Pragma("unroll") for (int i = 0; i < 4; ++i)                               \
        _Pragma("unroll") for (int j = 0; j < 4; ++j)                           \
            acc[i][j] = __builtin_amdgcn_mfma_f32_16x16x32_bf16(                \
                af[i], bfr[j], acc[i][j], 0, 0, 0);                             \
  }

  STAGE_W(0, 0);
  STAGE_W(1, 32);
  asm volatile("s_waitcnt vmcnt(3)" ::: "memory");
  __builtin_amdgcn_s_barrier();

  int bufc = 0;
  for (int t = 0; t < 30; ++t) {
    int bufn = bufc + 2; if (bufn >= 3) bufn -= 3;
    STAGE_W(bufn, (t + 2) * 32);
    COMPUTE_W(bufc);
    asm volatile("s_waitcnt vmcnt(3)" ::: "memory");
    __builtin_amdgcn_s_barrier();
    bufc = (bufc == 2) ? 0 : bufc + 1;
  }
  COMPUTE_W(bufc);
  asm volatile("s_waitcnt vmcnt(0)" ::: "memory");
  __builtin_amdgcn_s_barrier();
  bufc = (bufc == 2) ? 0 : bufc + 1;
  COMPUTE_W(bufc);
#undef STAGE_W
#undef COMPUTE_W

#pragma unroll
  for (int i = 0; i < 4; ++i)
#pragma unroll
    for (int r = 0; r < 4; ++r) {
      const int m = m0 + wm + i * 16 + g * 4 + r;
#pragma unroll
      for (int j = 0; j < 4; ++j) {
        const int n = n0 + wn + j * 16 + d;
        O[(size_t)m * 1024 + n] = acc[i][j][r] + bias[n] + resid[(size_t)m * 1024 + n];
      }
    }
}

// ---------------- flash attention: kv-half split + ones-MFMA lsum (R12) ------
__global__ __launch_bounds__(512) void attn_kernel(
    const ushort_t* __restrict__ Q, const ushort_t* __restrict__ Kb,
    const ushort_t* __restrict__ VT, ushort_t* __restrict__ ctx)
{
  __shared__ uint4 KV[2048];   // 32KB: [2 bufs][K 512 | V 512], chunk^(row&7)
  __shared__ float Ls[256];    // half=1 lsum slots
  const int orig = blockIdx.x;
  const int wgid = (orig & 7) * 64 + (orig >> 3);   // cluster 4 bh per XCD
  const int bh = wgid >> 4;
  const int q0 = (wgid & 15) * 128;
  const int tid = threadIdx.x;
  const int wave = tid >> 6, lane = tid & 63;
  const int qw = wave >> 1, half = wave & 1;
  const int ql = lane & 31, h2 = lane >> 5;
  const int qrow = q0 + qw * 32 + ql;

  bf16x8 qf[4];
  {
    const ushort_t* qp = Q + ((size_t)bh * 2048 + qrow) * 64 + h2 * 8;
#pragma unroll
    for (int s = 0; s < 4; ++s)
      qf[s] = __builtin_bit_cast(bf16x8, *(const uint4*)(qp + 16 * s));
  }

  bf16x8 onesf;
  {
    uint4 ou = {0x3F803F80u, 0x3F803F80u, 0x3F803F80u, 0x3F803F80u};
    onesf = __builtin_bit_cast(bf16x8, ou);
  }

  const int st_row = tid >> 3, st_c8 = tid & 7;
  const ushort_t* kgp = Kb + (size_t)(bh * 2048 + st_row) * 64 + st_c8 * 8;
  const ushort_t* vgp = VT + (size_t)(bh * 64 + st_row) * 2048 + st_c8 * 8;
  const int sidx = st_row * 8 + (st_c8 ^ (st_row & 7));

  uint4 kr = *(const uint4*)(kgp);
  uint4 vr = *(const uint4*)(vgp);
  KV[sidx] = kr;
  KV[512 + sidx] = vr;
  __syncthreads();

  f32x16 cacc[2] = {};
  f32x16 lacc = {};

#define ATT_COMPUTE(CB)                                                         \
  {                                                                             \
    f32x16 z = {};                                                              \
    _Pragma("unroll") for (int s = 0; s < 4; ++s) {                             \
      bf16x8 kf = __builtin_bit_cast(bf16x8,                                    \
          KV[(CB) + (half * 32 + ql) * 8 + ((2 * s + h2) ^ (ql & 7))]);         \
      z = __builtin_amdgcn_mfma_f32_32x32x16_bf16(kf, qf[s], z, 0, 0, 0);       \
    }                                                                           \
    bf16x8 pf[2];                                                               \
    _Pragma("unroll") for (int s2 = 0; s2 < 2; ++s2) {                          \
      const int rb = s2 * 8;                                                    \
      float p0 = __builtin_amdgcn_exp2f(z[rb + 0]);                             \
      float p1 = __builtin_amdgcn_exp2f(z[rb + 1]);                             \
      float p2 = __builtin_amdgcn_exp2f(z[rb + 2]);                             \
      float p3 = __builtin_amdgcn_exp2f(z[rb + 3]);                             \
      float p4 = __builtin_amdgcn_exp2f(z[rb + 4]);                             \
      float p5 = __builtin_amdgcn_exp2f(z[rb + 5]);                             \
      float p6 = __builtin_amdgcn_exp2f(z[rb + 6]);                             \
      float p7 = __builtin_amdgcn_exp2f(z[rb + 7]);                             \
      uint32_t a1 = cvt_pk_bf16(p0, p1);                                        \
      uint32_t a2 = cvt_pk_bf16(p2, p3);                                        \
      uint32_t b1 = cvt_pk_bf16(p4, p5);                                        \
      uint32_t b2 = cvt_pk_bf16(p6, p7);                                        \
      permswap(a1, b1);                                                         \
      permswap(a2, b2);                                                         \
      uint4 u = {a1, a2, b1, b2};                                               \
      pf[s2] = __builtin_bit_cast(bf16x8, u);                                   \
    }                                                                           \
    _Pragma("unroll") for (int s2 = 0; s2 < 2; ++s2)                            \
      lacc = __builtin_amdgcn_mfma_f32_32x32x16_bf16(onesf, pf[s2], lacc,       \
                                                     0, 0, 0);                  \
    _Pragma("unroll") for (int dt = 0; dt < 2; ++dt)                            \
      _Pragma("unroll") for (int s2 = 0; s2 < 2; ++s2) {                        \
        const int s = 2 * half + s2;                                            \
        bf16x8 vf = __builtin_bit_cast(bf16x8,                                  \
            KV[(CB) + 512 + (dt * 32 + ql) * 8 + ((2 * s + h2) ^ (ql & 7))]);   \
        cacc[dt] = __builtin_amdgcn_mfma_f32_32x32x16_bf16(vf, pf[s2],          \
                                                           cacc[dt], 0, 0, 0); \
      }                                                                         \
  }

  const ushort_t* kP = kgp + 4096;   // tile 1 (64 rows x 64 elems)
  const ushort_t* vP = vgp + 64;
  for (int tt = 0; tt < 16; ++tt) {
    kr = *(const uint4*)(kP);
    vr = *(const uint4*)(vP);
    ATT_COMPUTE(0)
    KV[1024 + sidx] = kr;
    KV[1536 + sidx] = vr;
    __syncthreads();
    if (tt < 15) {
      kr = *(const uint4*)(kP + 4096);
      vr = *(const uint4*)(vP + 64);
    }
    ATT_COMPUTE(1024)
    if (tt < 15) {
      KV[sidx] = kr;
      KV[512 + sidx] = vr;
      __syncthreads();
    }
    kP += 8192;
    vP += 128;
  }
#undef ATT_COMPUTE

  float lsum = lacc[0];

  __syncthreads();
  float* Lf = (float*)KV;
  const int slot = qw * 64 + lane;          // 0..255
  if (half == 1) {
#pragma unroll
    for (int dt = 0; dt < 2; ++dt)
#pragma unroll
      for (int r = 0; r < 16; ++r)
        Lf[slot * 32 + ((dt * 16 + r) ^ (lane & 31))] = cacc[dt][r];
    Ls[slot] = lsum;
  }
  __syncthreads();
  if (half == 0) {
#pragma unroll
    for (int dt = 0; dt < 2; ++dt)
#pragma unroll
      for (int r = 0; r < 16; ++r)
        cacc[dt][r] += Lf[slot * 32 + ((dt * 16 + r) ^ (lane & 31))];
    lsum += Ls[slot];

    const float rinv = 1.0f / lsum;
    const int b = bh >> 4, h = bh & 15;
    ushort_t* cp = ctx + ((size_t)(b * 2048 + qrow)) * 1024 + h * 64 + h2 * 4;
#pragma unroll
    for (int dt = 0; dt < 2; ++dt)
#pragma unroll
      for (int t = 0; t < 4; ++t) {
        uint2 w;
        w.x = cvt_pk_bf16(cacc[dt][4 * t + 0] * rinv, cacc[dt][4 * t + 1] * rinv);
        w.y = cvt_pk_bf16(cacc[dt][4 * t + 2] * rinv, cacc[dt][4 * t + 3] * rinv);
        *(uint2*)(cp + dt * 32 + t * 8) = w;   // hd = 32dt + 8t + 4h2 + 0..3
      }
  }
}

// ---------------- LayerNorm over rows of 1024 ----------------
__global__ __launch_bounds__(256) void ln_kernel(const float* __restrict__ x,
    const float* __restrict__ w, const float* __restrict__ b2, float* __restrict__ out)
{
  const int row = blockIdx.x, tid = threadIdx.x;
  const float4 v = ((const float4*)(x + (size_t)row * 1024))[tid];
  float s = v.x + v.y + v.z + v.w;
  float ss = v.x * v.x + v.y * v.y + v.z * v.z + v.w * v.w;
#pragma unroll
  for (int off = 32; off > 0; off >>= 1) {
    s += __shfl_down(s, off, 64);
    ss += __shfl_down(ss, off, 64);
  }
  __shared__ float red[8];
  if ((tid & 63) == 0) { red[tid >> 6] = s; red[4 + (tid >> 6)] = ss; }
  __syncthreads();
  const float S = red[0] + red[1] + red[2] + red[3];
  const float SS = red[4] + red[5] + red[6] + red[7];
  const float mu = S * (1.f / 1024.f);
  const float rstd = rsqrtf(SS * (1.f / 1024.f) - mu * mu + 1e-12f);
  const int c = tid * 4;
  float4 o;
  o.x = (v.x - mu) * rstd * w[c + 0] + b2[c + 0];
  o.y = (v.y - mu) * rstd * w[c + 1] + b2[c + 1];
  o.z = (v.z - mu) * rstd * w[c + 2] + b2[c + 2];
  o.w = (v.w - mu) * rstd * w[c + 3] + b2[c + 3];
  ((float4*)(out + (size_t)row * 1024))[tid] = o;
}

// ---------------- launch ----------------
extern "C" void kernel_launch(void* const* d_in, const int* in_sizes, int n_in,
                              void* d_out, int out_size, void* d_ws, size_t ws_size,
                              hipStream_t stream) {
  const float* hidden = (const float*)d_in[0];
  const float* cosT = (const float*)d_in[1];
  const float* sinT = (const float*)d_in[2];
  const float* Wq = (const float*)d_in[3];
  const float* bq = (const float*)d_in[4];
  const float* Wk = (const float*)d_in[5];
  const float* bk = (const float*)d_in[6];
  const float* Wv = (const float*)d_in[7];
  const float* bv = (const float*)d_in[8];
  const float* Wo = (const float*)d_in[9];
  const float* bo = (const float*)d_in[10];
  const float* lnw = (const float*)d_in[11];
  const float* lnb = (const float*)d_in[12];

  char* ws = (char*)d_ws;
  const size_t MB = 1u << 20;
  ushort_t* hid_bf = (ushort_t*)(ws);
  ushort_t* wq_bf = (ushort_t*)(ws + 8 * MB);
  ushort_t* wk_bf = (ushort_t*)(ws + 10 * MB);
  ushort_t* wv_bf = (ushort_t*)(ws + 12 * MB);
  ushort_t* wo_bf = (ushort_t*)(ws + 14 * MB);
  ushort_t* q_buf = (ushort_t*)(ws + 16 * MB);
  ushort_t* k_buf = (ushort_t*)(ws + 24 * MB);
  ushort_t* vt_buf = (ushort_t*)(ws + 32 * MB);
  ushort_t* ctx_bf = (ushort_t*)(ws + 40 * MB);
  float* out_pre = (float*)(ws + 16 * MB);   // aliases q+k (dead by then)

  cast_all_kernel<<<4096, 256, 0, stream>>>(hidden, Wq, Wk, Wv, Wo,
                                            hid_bf, wq_bf, wk_bf, wv_bf, wo_bf);

  gemm_qkv<<<dim3(16, 8, 3), 512, 0, stream>>>(hid_bf, wq_bf, wk_bf, wv_bf,
                                               bq, bk, bv, cosT, sinT,
                                               q_buf, k_buf, vt_buf);
  attn_kernel<<<512, 512, 0, stream>>>(q_buf, k_buf, vt_buf, ctx_bf);
  gemm_wo<<<dim3(16, 8), 512, 0, stream>>>(ctx_bf, wo_bf, bo, hidden, out_pre);
  ln_kernel<<<4096, 256, 0, stream>>>(out_pre, lnw, lnb, (float*)d_out);
}

// Round 14
// 113.359 us; speedup vs baseline: 1.1086x; 1.1086x over previous
//
#include <hip/hip_runtime.h>
#include <hip/hip_bf16.h>
#include <stdint.h>

// Problem constants: B=2, S=2048, D=1024, H=16, HD=64.
// ws layout (MB): 0 hid_bf | 8 wq | 10 wk | 12 wv | 14 wo | 16 q (8MB) | 24 k (8MB)
//                 | 32 vt (8MB) | 40 ctx (8MB);  out_pre(f32,16MB) aliases q+k @16MB.

typedef unsigned short ushort_t;
typedef short bf16x8 __attribute__((ext_vector_type(8)));
typedef float f32x4 __attribute__((ext_vector_type(4)));
typedef float f32x16 __attribute__((ext_vector_type(16)));
typedef unsigned short ushort8 __attribute__((ext_vector_type(8)));

#define LOG2E 1.4426950408889634f

__device__ __forceinline__ ushort_t f2b(float f) {
  uint32_t x = __builtin_bit_cast(uint32_t, f);
  return (ushort_t)((x + 0x7FFFu + ((x >> 16) & 1u)) >> 16);
}

__device__ __forceinline__ uint32_t cvt_pk_bf16(float lo, float hi) {
  uint32_t r;
  asm("v_cvt_pk_bf16_f32 %0, %1, %2" : "=v"(r) : "v"(lo), "v"(hi));
  return r;
}

// a.upper <-> b.lower halves across the 32-lane boundary
__device__ __forceinline__ void permswap(uint32_t& a, uint32_t& b) {
  asm volatile("v_permlane32_swap_b32 %0, %1" : "+v"(a), "+v"(b));
}

__device__ __forceinline__ void gload16(const void* gptr, void* ldsptr) {
  __builtin_amdgcn_global_load_lds(
      (const __attribute__((address_space(1))) uint32_t*)gptr,
      (__attribute__((address_space(3))) uint32_t*)ldsptr, 16, 0, 0);
}

// ---------------- fused cast fp32 -> bf16 (hidden + 4 weights, one launch) ---
__global__ void cast_all_kernel(const float* __restrict__ h,
                                const float* __restrict__ a, const float* __restrict__ b,
                                const float* __restrict__ c, const float* __restrict__ d2,
                                ushort_t* __restrict__ oh, ushort_t* __restrict__ oa,
                                ushort_t* __restrict__ ob, ushort_t* __restrict__ oc,
                                ushort_t* __restrict__ od) {
  const int blk = blockIdx.x;
  const float* src;
  ushort_t* dst;
  int rel;
  if (blk < 2048) { src = h; dst = oh; rel = blk; }
  else {
    const int w = (blk - 2048) >> 9;
    rel = (blk - 2048) & 511;
    src = w == 0 ? a : w == 1 ? b : w == 2 ? c : d2;
    dst = w == 0 ? oa : w == 1 ? ob : w == 2 ? oc : od;
  }
  const int i = (rel * 256 + threadIdx.x) * 8;
  const float4* s = (const float4*)(src + i);
  float4 x = s[0], y = s[1];
  ushort8 o = { f2b(x.x), f2b(x.y), f2b(x.z), f2b(x.w),
                f2b(y.x), f2b(y.y), f2b(y.z), f2b(y.w) };
  *(ushort8*)(dst + i) = o;
}

// ---------------- fused QKV projection GEMM (R12, proven) ---------------------
// 128x128 tile, BK=32, 4 waves. T4 counted-vmcnt pipeline: 3 LDS buffers,
// per step issue STAGE(buf[t+2]) -> MFMA buf[t] -> s_waitcnt vmcnt(4) (oldest
// 4 loads = buf[t+1] done) -> RAW s_barrier (no vmcnt(0) drain in main loop).
// which = blockIdx.z: 0 -> Q (RoPE + scale), 1 -> K (RoPE), 2 -> V^T
__global__ __launch_bounds__(256) void gemm_qkv(
    const ushort_t* __restrict__ hid, const ushort_t* __restrict__ wq,
    const ushort_t* __restrict__ wk, const ushort_t* __restrict__ wv,
    const float* __restrict__ bq, const float* __restrict__ bk,
    const float* __restrict__ bv, const float* __restrict__ cosT,
    const float* __restrict__ sinT, ushort_t* __restrict__ qout,
    ushort_t* __restrict__ kout, ushort_t* __restrict__ vtout)
{
  constexpr int K = 1024;
  __shared__ uint4 SB[3072];   // 48KB: 3 bufs x [A 512 | B 512] uint4
  const int which = blockIdx.z;
  const ushort_t* A;
  const ushort_t* Bm;
  const float* bias;
  int m0, n0;
  if (which == 0)      { A = hid; Bm = wq; bias = bq; m0 = blockIdx.x * 128; n0 = blockIdx.y * 128; }
  else if (which == 1) { A = hid; Bm = wk; bias = bk; m0 = blockIdx.x * 128; n0 = blockIdx.y * 128; }
  else                 { A = wv;  Bm = hid; bias = bv; m0 = blockIdx.y * 128; n0 = blockIdx.x * 128; }

  const int tid = threadIdx.x;
  const int wave = tid >> 6, lane = tid & 63;
  const int d = lane & 15, g = lane >> 4;
  const int wm = (wave >> 1) * 64, wn = (wave & 1) * 64;

  const ushort_t* ag = A + (size_t)(m0 + (tid >> 2)) * K + (tid & 3) * 8;
  const ushort_t* bg = Bm + (size_t)(n0 + (tid >> 2)) * K + (tid & 3) * 8;

  f32x4 acc[4][4] = {};

#define STAGE_Q(buf, k0)                                           \
  {                                                                \
    char* dst = (char*)SB + (buf) * 16384 + wave * 1024;           \
    gload16(ag + (k0), dst);                                       \
    gload16(ag + 64 * K + (k0), dst + 4096);                       \
    gload16(bg + (k0), dst + 8192);                                \
    gload16(bg + 64 * K + (k0), dst + 12288);                      \
  }

#define COMPUTE_Q(buf)                                                          \
  {                                                                             \
    bf16x8 af[4], bfr[4];                                                       \
    _Pragma("unroll") for (int i = 0; i < 4; ++i)                               \
        af[i] = __builtin_bit_cast(bf16x8,                                      \
            SB[(buf) * 1024 + (wm + i * 16 + d) * 4 + g]);                      \
    _Pragma("unroll") for (int j = 0; j < 4; ++j)                               \
        bfr[j] = __builtin_bit_cast(bf16x8,                                     \
            SB[(buf) * 1024 + 512 + (wn + j * 16 + d) * 4 + g]);                \
    _Pragma("unroll") for (int i = 0; i < 4; ++i)                               \
        _Pragma("unroll") for (int j = 0; j < 4; ++j)                           \
            acc[i][j] = __builtin_amdgcn_mfma_f32_16x16x32_bf16(                \
                af[i], bfr[j], acc[i][j], 0, 0, 0);                             \
  }

  STAGE_Q(0, 0);
  STAGE_Q(1, 32);
  asm volatile("s_waitcnt vmcnt(4)" ::: "memory");
  __builtin_amdgcn_s_barrier();

  int bufc = 0;
  for (int t = 0; t < 30; ++t) {
    int bufn = bufc + 2; if (bufn >= 3) bufn -= 3;
    STAGE_Q(bufn, (t + 2) * 32);
    COMPUTE_Q(bufc);
    asm volatile("s_waitcnt vmcnt(4)" ::: "memory");   // buf[t+1] complete
    __builtin_amdgcn_s_barrier();
    bufc = (bufc == 2) ? 0 : bufc + 1;
  }
  COMPUTE_Q(bufc);
  asm volatile("s_waitcnt vmcnt(0)" ::: "memory");
  __builtin_amdgcn_s_barrier();
  bufc = (bufc == 2) ? 0 : bufc + 1;
  COMPUTE_Q(bufc);
#undef STAGE_Q
#undef COMPUTE_Q

  if (which <= 1) {
    ushort_t* O = which == 0 ? qout : kout;
    const float qscale = which == 0 ? (LOG2E / 64.0f) : 1.0f;
    const int head_base = n0 + wn;
    const int h = head_base >> 6;
#pragma unroll
    for (int i = 0; i < 4; ++i) {
#pragma unroll
      for (int r = 0; r < 4; ++r) {
        const int m = m0 + wm + i * 16 + g * 4 + r;
        const int s = m & 2047, b = m >> 11;
#pragma unroll
        for (int j = 0; j < 4; ++j) {
          const int c = j * 16 + d;
          const float v0 = acc[i][j][r] + bias[head_base + c];
          const float v1 = acc[i][j ^ 2][r] + bias[head_base + (c ^ 32)];
          const float rot = (c < 32) ? -v1 : v1;
          const float vr = (v0 * cosT[s * 64 + c] + rot * sinT[s * 64 + c]) * qscale;
          O[(size_t)(((b << 4) + h) * 2048 + s) * 64 + c] = f2b(vr);
        }
      }
    }
  } else {
    ushort_t* O = vtout;
#pragma unroll
    for (int i = 0; i < 4; ++i) {
#pragma unroll
      for (int r = 0; r < 4; ++r) {
        const int fr = m0 + wm + i * 16 + g * 4 + r;
        const float bv2 = bias[fr];
        const int h = fr >> 6, dd = fr & 63;
#pragma unroll
        for (int j = 0; j < 4; ++j) {
          const int tok = n0 + wn + j * 16 + d;
          const int b = tok >> 11, s = tok & 2047;
          O[(size_t)(((b << 4) + h) * 64 + dd) * 2048 + s] = f2b(acc[i][j][r] + bv2);
        }
      }
    }
  }
}

// ---------------- Wo GEMM: 128x64 tile, T4 pipeline, 512 blocks --------------
// R13 lesson: wo at 128x128 = 256 blocks = 1 block/CU (4 waves) is latency-
// exposed. 128x64 -> grid (32,16) = 512 blocks = 2/CU (8 waves), LDS 36KB,
// 3 loads/thread/step -> vmcnt(3), 8 MFMA/wave/step.
__global__ __launch_bounds__(256) void gemm_wo(
    const ushort_t* __restrict__ A, const ushort_t* __restrict__ B,
    const float* __restrict__ bias, const float* __restrict__ resid,
    float* __restrict__ O)
{
  constexpr int K = 1024;
  __shared__ uint4 SBa[1536];   // 24KB: 3 bufs x 128 rows x 4 chunks
  __shared__ uint4 SBb[768];    // 12KB: 3 bufs x 64 rows x 4 chunks
  const int tid = threadIdx.x;
  const int wave = tid >> 6, lane = tid & 63;
  const int d = lane & 15, g = lane >> 4;
  const int m0 = blockIdx.x * 128, n0 = blockIdx.y * 64;
  const int wm = (wave >> 1) * 64, wn = (wave & 1) * 32;

  const ushort_t* ag = A + (size_t)(m0 + (tid >> 2)) * K + (tid & 3) * 8;
  const ushort_t* bg = B + (size_t)(n0 + (tid >> 2)) * K + (tid & 3) * 8;

  f32x4 acc[4][2] = {};

#define STAGE_W(buf, k0)                                           \
  {                                                                \
    char* da = (char*)(SBa + (buf) * 512) + wave * 1024;           \
    char* db = (char*)(SBb + (buf) * 256) + wave * 1024;           \
    gload16(ag + (k0), da);                                        \
    gload16(ag + 64 * K + (k0), da + 4096);                        \
    gload16(bg + (k0), db);                                        \
  }

#define COMPUTE_W(buf)                                                          \
  {                                                                             \
    bf16x8 af[4], bfr[2];                                                       \
    _Pragma("unroll") for (int i = 0; i < 4; ++i)                               \
        af[i] = __builtin_bit_cast(bf16x8,                                      \
            SBa[(buf) * 512 + (wm + i * 16 + d) * 4 + g]);                      \
    _Pragma("unroll") for (int j = 0; j < 2; ++j)                               \
        bfr[j] = __builtin_bit_cast(bf16x8,                                     \
            SBb[(buf) * 256 + (wn + j * 16 + d) * 4 + g]);                      \
    _Pragma("unroll") for (int i = 0; i < 4; ++i)                               \
        _Pragma("unroll") for (int j = 0; j < 2; ++j)                           \
            acc[i][j] = __builtin_amdgcn_mfma_f32_16x16x32_bf16(                \
                af[i], bfr[j], acc[i][j], 0, 0, 0);                             \
  }

  STAGE_W(0, 0);
  STAGE_W(1, 32);
  asm volatile("s_waitcnt vmcnt(3)" ::: "memory");
  __builtin_amdgcn_s_barrier();

  int bufc = 0;
  for (int t = 0; t < 30; ++t) {
    int bufn = bufc + 2; if (bufn >= 3) bufn -= 3;
    STAGE_W(bufn, (t + 2) * 32);
    COMPUTE_W(bufc);
    asm volatile("s_waitcnt vmcnt(3)" ::: "memory");
    __builtin_amdgcn_s_barrier();
    bufc = (bufc == 2) ? 0 : bufc + 1;
  }
  COMPUTE_W(bufc);
  asm volatile("s_waitcnt vmcnt(0)" ::: "memory");
  __builtin_amdgcn_s_barrier();
  bufc = (bufc == 2) ? 0 : bufc + 1;
  COMPUTE_W(bufc);
#undef STAGE_W
#undef COMPUTE_W

#pragma unroll
  for (int i = 0; i < 4; ++i)
#pragma unroll
    for (int r = 0; r < 4; ++r) {
      const int m = m0 + wm + i * 16 + g * 4 + r;
#pragma unroll
      for (int j = 0; j < 2; ++j) {
        const int n = n0 + wn + j * 16 + d;
        O[(size_t)m * 1024 + n] = acc[i][j][r] + bias[n] + resid[(size_t)m * 1024 + n];
      }
    }
}

// ---------------- flash attention: kv-half split + ones-MFMA lsum (R12) ------
__global__ __launch_bounds__(512) void attn_kernel(
    const ushort_t* __restrict__ Q, const ushort_t* __restrict__ Kb,
    const ushort_t* __restrict__ VT, ushort_t* __restrict__ ctx)
{
  __shared__ uint4 KV[2048];   // 32KB: [2 bufs][K 512 | V 512], chunk^(row&7)
  __shared__ float Ls[256];    // half=1 lsum slots
  const int orig = blockIdx.x;
  const int wgid = (orig & 7) * 64 + (orig >> 3);   // cluster 4 bh per XCD
  const int bh = wgid >> 4;
  const int q0 = (wgid & 15) * 128;
  const int tid = threadIdx.x;
  const int wave = tid >> 6, lane = tid & 63;
  const int qw = wave >> 1, half = wave & 1;
  const int ql = lane & 31, h2 = lane >> 5;
  const int qrow = q0 + qw * 32 + ql;

  bf16x8 qf[4];
  {
    const ushort_t* qp = Q + ((size_t)bh * 2048 + qrow) * 64 + h2 * 8;
#pragma unroll
    for (int s = 0; s < 4; ++s)
      qf[s] = __builtin_bit_cast(bf16x8, *(const uint4*)(qp + 16 * s));
  }

  bf16x8 onesf;
  {
    uint4 ou = {0x3F803F80u, 0x3F803F80u, 0x3F803F80u, 0x3F803F80u};
    onesf = __builtin_bit_cast(bf16x8, ou);
  }

  const int st_row = tid >> 3, st_c8 = tid & 7;
  const ushort_t* kgp = Kb + (size_t)(bh * 2048 + st_row) * 64 + st_c8 * 8;
  const ushort_t* vgp = VT + (size_t)(bh * 64 + st_row) * 2048 + st_c8 * 8;
  const int sidx = st_row * 8 + (st_c8 ^ (st_row & 7));

  uint4 kr = *(const uint4*)(kgp);
  uint4 vr = *(const uint4*)(vgp);
  KV[sidx] = kr;
  KV[512 + sidx] = vr;
  __syncthreads();

  f32x16 cacc[2] = {};
  f32x16 lacc = {};

#define ATT_COMPUTE(CB)                                                         \
  {                                                                             \
    f32x16 z = {};                                                              \
    _Pragma("unroll") for (int s = 0; s < 4; ++s) {                             \
      bf16x8 kf = __builtin_bit_cast(bf16x8,                                    \
          KV[(CB) + (half * 32 + ql) * 8 + ((2 * s + h2) ^ (ql & 7))]);         \
      z = __builtin_amdgcn_mfma_f32_32x32x16_bf16(kf, qf[s], z, 0, 0, 0);       \
    }                                                                           \
    bf16x8 pf[2];                                                               \
    _Pragma("unroll") for (int s2 = 0; s2 < 2; ++s2) {                          \
      const int rb = s2 * 8;                                                    \
      float p0 = __builtin_amdgcn_exp2f(z[rb + 0]);                             \
      float p1 = __builtin_amdgcn_exp2f(z[rb + 1]);                             \
      float p2 = __builtin_amdgcn_exp2f(z[rb + 2]);                             \
      float p3 = __builtin_amdgcn_exp2f(z[rb + 3]);                             \
      float p4 = __builtin_amdgcn_exp2f(z[rb + 4]);                             \
      float p5 = __builtin_amdgcn_exp2f(z[rb + 5]);                             \
      float p6 = __builtin_amdgcn_exp2f(z[rb + 6]);                             \
      float p7 = __builtin_amdgcn_exp2f(z[rb + 7]);                             \
      uint32_t a1 = cvt_pk_bf16(p0, p1);                                        \
      uint32_t a2 = cvt_pk_bf16(p2, p3);                                        \
      uint32_t b1 = cvt_pk_bf16(p4, p5);                                        \
      uint32_t b2 = cvt_pk_bf16(p6, p7);                                        \
      permswap(a1, b1);                                                         \
      permswap(a2, b2);                                                         \
      uint4 u = {a1, a2, b1, b2};                                               \
      pf[s2] = __builtin_bit_cast(bf16x8, u);                                   \
    }                                                                           \
    _Pragma("unroll") for (int s2 = 0; s2 < 2; ++s2)                            \
      lacc = __builtin_amdgcn_mfma_f32_32x32x16_bf16(onesf, pf[s2], lacc,       \
                                                     0, 0, 0);                  \
    _Pragma("unroll") for (int dt = 0; dt < 2; ++dt)                            \
      _Pragma("unroll") for (int s2 = 0; s2 < 2; ++s2) {                        \
        const int s = 2 * half + s2;                                            \
        bf16x8 vf = __builtin_bit_cast(bf16x8,                                  \
            KV[(CB) + 512 + (dt * 32 + ql) * 8 + ((2 * s + h2) ^ (ql & 7))]);   \
        cacc[dt] = __builtin_amdgcn_mfma_f32_32x32x16_bf16(vf, pf[s2],          \
                                                           cacc[dt], 0, 0, 0); \
      }                                                                         \
  }

  const ushort_t* kP = kgp + 4096;   // tile 1 (64 rows x 64 elems)
  const ushort_t* vP = vgp + 64;
  for (int tt = 0; tt < 16; ++tt) {
    kr = *(const uint4*)(kP);
    vr = *(const uint4*)(vP);
    ATT_COMPUTE(0)
    KV[1024 + sidx] = kr;
    KV[1536 + sidx] = vr;
    __syncthreads();
    if (tt < 15) {
      kr = *(const uint4*)(kP + 4096);
      vr = *(const uint4*)(vP + 64);
    }
    ATT_COMPUTE(1024)
    if (tt < 15) {
      KV[sidx] = kr;
      KV[512 + sidx] = vr;
      __syncthreads();
    }
    kP += 8192;
    vP += 128;
  }
#undef ATT_COMPUTE

  float lsum = lacc[0];

  __syncthreads();
  float* Lf = (float*)KV;
  const int slot = qw * 64 + lane;          // 0..255
  if (half == 1) {
#pragma unroll
    for (int dt = 0; dt < 2; ++dt)
#pragma unroll
      for (int r = 0; r < 16; ++r)
        Lf[slot * 32 + ((dt * 16 + r) ^ (lane & 31))] = cacc[dt][r];
    Ls[slot] = lsum;
  }
  __syncthreads();
  if (half == 0) {
#pragma unroll
    for (int dt = 0; dt < 2; ++dt)
#pragma unroll
      for (int r = 0; r < 16; ++r)
        cacc[dt][r] += Lf[slot * 32 + ((dt * 16 + r) ^ (lane & 31))];
    lsum += Ls[slot];

    const float rinv = 1.0f / lsum;
    const int b = bh >> 4, h = bh & 15;
    ushort_t* cp = ctx + ((size_t)(b * 2048 + qrow)) * 1024 + h * 64 + h2 * 4;
#pragma unroll
    for (int dt = 0; dt < 2; ++dt)
#pragma unroll
      for (int t = 0; t < 4; ++t) {
        uint2 w;
        w.x = cvt_pk_bf16(cacc[dt][4 * t + 0] * rinv, cacc[dt][4 * t + 1] * rinv);
        w.y = cvt_pk_bf16(cacc[dt][4 * t + 2] * rinv, cacc[dt][4 * t + 3] * rinv);
        *(uint2*)(cp + dt * 32 + t * 8) = w;   // hd = 32dt + 8t + 4h2 + 0..3
      }
  }
}

// ---------------- LayerNorm over rows of 1024 ----------------
__global__ __launch_bounds__(256) void ln_kernel(const float* __restrict__ x,
    const float* __restrict__ w, const float* __restrict__ b2, float* __restrict__ out)
{
  const int row = blockIdx.x, tid = threadIdx.x;
  const float4 v = ((const float4*)(x + (size_t)row * 1024))[tid];
  float s = v.x + v.y + v.z + v.w;
  float ss = v.x * v.x + v.y * v.y + v.z * v.z + v.w * v.w;
#pragma unroll
  for (int off = 32; off > 0; off >>= 1) {
    s += __shfl_down(s, off, 64);
    ss += __shfl_down(ss, off, 64);
  }
  __shared__ float red[8];
  if ((tid & 63) == 0) { red[tid >> 6] = s; red[4 + (tid >> 6)] = ss; }
  __syncthreads();
  const float S = red[0] + red[1] + red[2] + red[3];
  const float SS = red[4] + red[5] + red[6] + red[7];
  const float mu = S * (1.f / 1024.f);
  const float rstd = rsqrtf(SS * (1.f / 1024.f) - mu * mu + 1e-12f);
  const int c = tid * 4;
  float4 o;
  o.x = (v.x - mu) * rstd * w[c + 0] + b2[c + 0];
  o.y = (v.y - mu) * rstd * w[c + 1] + b2[c + 1];
  o.z = (v.z - mu) * rstd * w[c + 2] + b2[c + 2];
  o.w = (v.w - mu) * rstd * w[c + 3] + b2[c + 3];
  ((float4*)(out + (size_t)row * 1024))[tid] = o;
}

// ---------------- launch ----------------
extern "C" void kernel_launch(void* const* d_in, const int* in_sizes, int n_in,
                              void* d_out, int out_size, void* d_ws, size_t ws_size,
                              hipStream_t stream) {
  const float* hidden = (const float*)d_in[0];
  const float* cosT = (const float*)d_in[1];
  const float* sinT = (const float*)d_in[2];
  const float* Wq = (const float*)d_in[3];
  const float* bq = (const float*)d_in[4];
  const float* Wk = (const float*)d_in[5];
  const float* bk = (const float*)d_in[6];
  const float* Wv = (const float*)d_in[7];
  const float* bv = (const float*)d_in[8];
  const float* Wo = (const float*)d_in[9];
  const float* bo = (const float*)d_in[10];
  const float* lnw = (const float*)d_in[11];
  const float* lnb = (const float*)d_in[12];

  char* ws = (char*)d_ws;
  const size_t MB = 1u << 20;
  ushort_t* hid_bf = (ushort_t*)(ws);
  ushort_t* wq_bf = (ushort_t*)(ws + 8 * MB);
  ushort_t* wk_bf = (ushort_t*)(ws + 10 * MB);
  ushort_t* wv_bf = (ushort_t*)(ws + 12 * MB);
  ushort_t* wo_bf = (ushort_t*)(ws + 14 * MB);
  ushort_t* q_buf = (ushort_t*)(ws + 16 * MB);
  ushort_t* k_buf = (ushort_t*)(ws + 24 * MB);
  ushort_t* vt_buf = (ushort_t*)(ws + 32 * MB);
  ushort_t* ctx_bf = (ushort_t*)(ws + 40 * MB);
  float* out_pre = (float*)(ws + 16 * MB);   // aliases q+k (dead by then)

  cast_all_kernel<<<4096, 256, 0, stream>>>(hidden, Wq, Wk, Wv, Wo,
                                            hid_bf, wq_bf, wk_bf, wv_bf, wo_bf);

  gemm_qkv<<<dim3(32, 8, 3), 256, 0, stream>>>(hid_bf, wq_bf, wk_bf, wv_bf,
                                               bq, bk, bv, cosT, sinT,
                                               q_buf, k_buf, vt_buf);
  attn_kernel<<<512, 512, 0, stream>>>(q_buf, k_buf, vt_buf, ctx_bf);
  gemm_wo<<<dim3(32, 16), 256, 0, stream>>>(ctx_bf, wo_bf, bo, hidden, out_pre);
  ln_kernel<<<4096, 256, 0, stream>>>(out_pre, lnw, lnb, (float*)d_out);
}

// Round 15
// 108.137 us; speedup vs baseline: 1.1621x; 1.0483x over previous
//
#include <hip/hip_runtime.h>
#include <hip/hip_bf16.h>
#include <stdint.h>

// Problem constants: B=2, S=2048, D=1024, H=16, HD=64.
// ws layout (MB): 0 hid_bf | 8 wq | 10 wk | 12 wv | 14 wo | 16 q (8MB) | 24 k (8MB)
//                 | 32 vt (8MB) | 40 ctx (8MB);  out_pre(bf16,8MB) aliases q @16MB.

typedef unsigned short ushort_t;
typedef short bf16x8 __attribute__((ext_vector_type(8)));
typedef float f32x4 __attribute__((ext_vector_type(4)));
typedef float f32x16 __attribute__((ext_vector_type(16)));
typedef unsigned short ushort8 __attribute__((ext_vector_type(8)));

#define LOG2E 1.4426950408889634f

__device__ __forceinline__ ushort_t f2b(float f) {
  uint32_t x = __builtin_bit_cast(uint32_t, f);
  return (ushort_t)((x + 0x7FFFu + ((x >> 16) & 1u)) >> 16);
}

__device__ __forceinline__ float b2f(ushort_t u) {
  return __builtin_bit_cast(float, (uint32_t)u << 16);
}

__device__ __forceinline__ uint32_t cvt_pk_bf16(float lo, float hi) {
  uint32_t r;
  asm("v_cvt_pk_bf16_f32 %0, %1, %2" : "=v"(r) : "v"(lo), "v"(hi));
  return r;
}

// a.upper <-> b.lower halves across the 32-lane boundary
__device__ __forceinline__ void permswap(uint32_t& a, uint32_t& b) {
  asm volatile("v_permlane32_swap_b32 %0, %1" : "+v"(a), "+v"(b));
}

__device__ __forceinline__ void gload16(const void* gptr, void* ldsptr) {
  __builtin_amdgcn_global_load_lds(
      (const __attribute__((address_space(1))) uint32_t*)gptr,
      (__attribute__((address_space(3))) uint32_t*)ldsptr, 16, 0, 0);
}

// ---------------- fused cast fp32 -> bf16 (hidden + 4 weights, one launch) ---
__global__ void cast_all_kernel(const float* __restrict__ h,
                                const float* __restrict__ a, const float* __restrict__ b,
                                const float* __restrict__ c, const float* __restrict__ d2,
                                ushort_t* __restrict__ oh, ushort_t* __restrict__ oa,
                                ushort_t* __restrict__ ob, ushort_t* __restrict__ oc,
                                ushort_t* __restrict__ od) {
  const int blk = blockIdx.x;
  const float* src;
  ushort_t* dst;
  int rel;
  if (blk < 2048) { src = h; dst = oh; rel = blk; }
  else {
    const int w = (blk - 2048) >> 9;
    rel = (blk - 2048) & 511;
    src = w == 0 ? a : w == 1 ? b : w == 2 ? c : d2;
    dst = w == 0 ? oa : w == 1 ? ob : w == 2 ? oc : od;
  }
  const int i = (rel * 256 + threadIdx.x) * 8;
  const float4* s = (const float4*)(src + i);
  float4 x = s[0], y = s[1];
  ushort8 o = { f2b(x.x), f2b(x.y), f2b(x.z), f2b(x.w),
                f2b(y.x), f2b(y.y), f2b(y.z), f2b(y.w) };
  *(ushort8*)(dst + i) = o;
}

// ---------------- fused QKV projection GEMM (R12, proven) ---------------------
// 128x128 tile, BK=32, 4 waves. T4 counted-vmcnt pipeline: 3 LDS buffers,
// per step issue STAGE(buf[t+2]) -> MFMA buf[t] -> s_waitcnt vmcnt(4) (oldest
// 4 loads = buf[t+1] done) -> RAW s_barrier (no vmcnt(0) drain in main loop).
// which = blockIdx.z: 0 -> Q (RoPE + scale), 1 -> K (RoPE), 2 -> V^T
__global__ __launch_bounds__(256) void gemm_qkv(
    const ushort_t* __restrict__ hid, const ushort_t* __restrict__ wq,
    const ushort_t* __restrict__ wk, const ushort_t* __restrict__ wv,
    const float* __restrict__ bq, const float* __restrict__ bk,
    const float* __restrict__ bv, const float* __restrict__ cosT,
    const float* __restrict__ sinT, ushort_t* __restrict__ qout,
    ushort_t* __restrict__ kout, ushort_t* __restrict__ vtout)
{
  constexpr int K = 1024;
  __shared__ uint4 SB[3072];   // 48KB: 3 bufs x [A 512 | B 512] uint4
  const int which = blockIdx.z;
  const ushort_t* A;
  const ushort_t* Bm;
  const float* bias;
  int m0, n0;
  if (which == 0)      { A = hid; Bm = wq; bias = bq; m0 = blockIdx.x * 128; n0 = blockIdx.y * 128; }
  else if (which == 1) { A = hid; Bm = wk; bias = bk; m0 = blockIdx.x * 128; n0 = blockIdx.y * 128; }
  else                 { A = wv;  Bm = hid; bias = bv; m0 = blockIdx.y * 128; n0 = blockIdx.x * 128; }

  const int tid = threadIdx.x;
  const int wave = tid >> 6, lane = tid & 63;
  const int d = lane & 15, g = lane >> 4;
  const int wm = (wave >> 1) * 64, wn = (wave & 1) * 64;

  const ushort_t* ag = A + (size_t)(m0 + (tid >> 2)) * K + (tid & 3) * 8;
  const ushort_t* bg = Bm + (size_t)(n0 + (tid >> 2)) * K + (tid & 3) * 8;

  f32x4 acc[4][4] = {};

#define STAGE_Q(buf, k0)                                           \
  {                                                                \
    char* dst = (char*)SB + (buf) * 16384 + wave * 1024;           \
    gload16(ag + (k0), dst);                                       \
    gload16(ag + 64 * K + (k0), dst + 4096);                       \
    gload16(bg + (k0), dst + 8192);                                \
    gload16(bg + 64 * K + (k0), dst + 12288);                      \
  }

#define COMPUTE_Q(buf)                                                          \
  {                                                                             \
    bf16x8 af[4], bfr[4];                                                       \
    _Pragma("unroll") for (int i = 0; i < 4; ++i)                               \
        af[i] = __builtin_bit_cast(bf16x8,                                      \
            SB[(buf) * 1024 + (wm + i * 16 + d) * 4 + g]);                      \
    _Pragma("unroll") for (int j = 0; j < 4; ++j)                               \
        bfr[j] = __builtin_bit_cast(bf16x8,                                     \
            SB[(buf) * 1024 + 512 + (wn + j * 16 + d) * 4 + g]);                \
    _Pragma("unroll") for (int i = 0; i < 4; ++i)                               \
        _Pragma("unroll") for (int j = 0; j < 4; ++j)                           \
            acc[i][j] = __builtin_amdgcn_mfma_f32_16x16x32_bf16(                \
                af[i], bfr[j], acc[i][j], 0, 0, 0);                             \
  }

  STAGE_Q(0, 0);
  STAGE_Q(1, 32);
  asm volatile("s_waitcnt vmcnt(4)" ::: "memory");
  __builtin_amdgcn_s_barrier();

  int bufc = 0;
  for (int t = 0; t < 30; ++t) {
    int bufn = bufc + 2; if (bufn >= 3) bufn -= 3;
    STAGE_Q(bufn, (t + 2) * 32);
    COMPUTE_Q(bufc);
    asm volatile("s_waitcnt vmcnt(4)" ::: "memory");   // buf[t+1] complete
    __builtin_amdgcn_s_barrier();
    bufc = (bufc == 2) ? 0 : bufc + 1;
  }
  COMPUTE_Q(bufc);
  asm volatile("s_waitcnt vmcnt(0)" ::: "memory");
  __builtin_amdgcn_s_barrier();
  bufc = (bufc == 2) ? 0 : bufc + 1;
  COMPUTE_Q(bufc);
#undef STAGE_Q
#undef COMPUTE_Q

  if (which <= 1) {
    ushort_t* O = which == 0 ? qout : kout;
    const float qscale = which == 0 ? (LOG2E / 64.0f) : 1.0f;
    const int head_base = n0 + wn;
    const int h = head_base >> 6;
#pragma unroll
    for (int i = 0; i < 4; ++i) {
#pragma unroll
      for (int r = 0; r < 4; ++r) {
        const int m = m0 + wm + i * 16 + g * 4 + r;
        const int s = m & 2047, b = m >> 11;
#pragma unroll
        for (int j = 0; j < 4; ++j) {
          const int c = j * 16 + d;
          const float v0 = acc[i][j][r] + bias[head_base + c];
          const float v1 = acc[i][j ^ 2][r] + bias[head_base + (c ^ 32)];
          const float rot = (c < 32) ? -v1 : v1;
          const float vr = (v0 * cosT[s * 64 + c] + rot * sinT[s * 64 + c]) * qscale;
          O[(size_t)(((b << 4) + h) * 2048 + s) * 64 + c] = f2b(vr);
        }
      }
    }
  } else {
    ushort_t* O = vtout;
#pragma unroll
    for (int i = 0; i < 4; ++i) {
#pragma unroll
      for (int r = 0; r < 4; ++r) {
        const int fr = m0 + wm + i * 16 + g * 4 + r;
        const float bv2 = bias[fr];
        const int h = fr >> 6, dd = fr & 63;
#pragma unroll
        for (int j = 0; j < 4; ++j) {
          const int tok = n0 + wn + j * 16 + d;
          const int b = tok >> 11, s = tok & 2047;
          O[(size_t)(((b << 4) + h) * 64 + dd) * 2048 + s] = f2b(acc[i][j][r] + bv2);
        }
      }
    }
  }
}

// ---------------- Wo GEMM (R12 structure; bias + residual, BF16 out) ---------
__global__ __launch_bounds__(256) void gemm_wo(
    const ushort_t* __restrict__ A, const ushort_t* __restrict__ B,
    const float* __restrict__ bias, const float* __restrict__ resid,
    ushort_t* __restrict__ O)
{
  constexpr int K = 1024;
  __shared__ uint4 SB[3072];
  const int tid = threadIdx.x;
  const int wave = tid >> 6, lane = tid & 63;
  const int d = lane & 15, g = lane >> 4;
  const int m0 = blockIdx.x * 128, n0 = blockIdx.y * 128;
  const int wm = (wave >> 1) * 64, wn = (wave & 1) * 64;

  const ushort_t* ag = A + (size_t)(m0 + (tid >> 2)) * K + (tid & 3) * 8;
  const ushort_t* bg = B + (size_t)(n0 + (tid >> 2)) * K + (tid & 3) * 8;

  f32x4 acc[4][4] = {};

#define STAGE_W(buf, k0)                                           \
  {                                                                \
    char* dst = (char*)SB + (buf) * 16384 + wave * 1024;           \
    gload16(ag + (k0), dst);                                       \
    gload16(ag + 64 * K + (k0), dst + 4096);                       \
    gload16(bg + (k0), dst + 8192);                                \
    gload16(bg + 64 * K + (k0), dst + 12288);                      \
  }

#define COMPUTE_W(buf)                                                          \
  {                                                                             \
    bf16x8 af[4], bfr[4];                                                       \
    _Pragma("unroll") for (int i = 0; i < 4; ++i)                               \
        af[i] = __builtin_bit_cast(bf16x8,                                      \
            SB[(buf) * 1024 + (wm + i * 16 + d) * 4 + g]);                      \
    _Pragma("unroll") for (int j = 0; j < 4; ++j)                               \
        bfr[j] = __builtin_bit_cast(bf16x8,                                     \
            SB[(buf) * 1024 + 512 + (wn + j * 16 + d) * 4 + g]);                \
    _Pragma("unroll") for (int i = 0; i < 4; ++i)                               \
        _Pragma("unroll") for (int j = 0; j < 4; ++j)                           \
            acc[i][j] = __builtin_amdgcn_mfma_f32_16x16x32_bf16(                \
                af[i], bfr[j], acc[i][j], 0, 0, 0);                             \
  }

  STAGE_W(0, 0);
  STAGE_W(1, 32);
  asm volatile("s_waitcnt vmcnt(4)" ::: "memory");
  __builtin_amdgcn_s_barrier();

  int bufc = 0;
  for (int t = 0; t < 30; ++t) {
    int bufn = bufc + 2; if (bufn >= 3) bufn -= 3;
    STAGE_W(bufn, (t + 2) * 32);
    COMPUTE_W(bufc);
    asm volatile("s_waitcnt vmcnt(4)" ::: "memory");
    __builtin_amdgcn_s_barrier();
    bufc = (bufc == 2) ? 0 : bufc + 1;
  }
  COMPUTE_W(bufc);
  asm volatile("s_waitcnt vmcnt(0)" ::: "memory");
  __builtin_amdgcn_s_barrier();
  bufc = (bufc == 2) ? 0 : bufc + 1;
  COMPUTE_W(bufc);
#undef STAGE_W
#undef COMPUTE_W

#pragma unroll
  for (int i = 0; i < 4; ++i)
#pragma unroll
    for (int r = 0; r < 4; ++r) {
      const int m = m0 + wm + i * 16 + g * 4 + r;
#pragma unroll
      for (int j = 0; j < 4; ++j) {
        const int n = n0 + wn + j * 16 + d;
        O[(size_t)m * 1024 + n] =
            f2b(acc[i][j][r] + bias[n] + resid[(size_t)m * 1024 + n]);
      }
    }
}

// ---------------- flash attention: kv-half split + ones-MFMA lsum (R12) ------
__global__ __launch_bounds__(512) void attn_kernel(
    const ushort_t* __restrict__ Q, const ushort_t* __restrict__ Kb,
    const ushort_t* __restrict__ VT, ushort_t* __restrict__ ctx)
{
  __shared__ uint4 KV[2048];   // 32KB: [2 bufs][K 512 | V 512], chunk^(row&7)
  __shared__ float Ls[256];    // half=1 lsum slots
  const int orig = blockIdx.x;
  const int wgid = (orig & 7) * 64 + (orig >> 3);   // cluster 4 bh per XCD
  const int bh = wgid >> 4;
  const int q0 = (wgid & 15) * 128;
  const int tid = threadIdx.x;
  const int wave = tid >> 6, lane = tid & 63;
  const int qw = wave >> 1, half = wave & 1;
  const int ql = lane & 31, h2 = lane >> 5;
  const int qrow = q0 + qw * 32 + ql;

  bf16x8 qf[4];
  {
    const ushort_t* qp = Q + ((size_t)bh * 2048 + qrow) * 64 + h2 * 8;
#pragma unroll
    for (int s = 0; s < 4; ++s)
      qf[s] = __builtin_bit_cast(bf16x8, *(const uint4*)(qp + 16 * s));
  }

  bf16x8 onesf;
  {
    uint4 ou = {0x3F803F80u, 0x3F803F80u, 0x3F803F80u, 0x3F803F80u};
    onesf = __builtin_bit_cast(bf16x8, ou);
  }

  const int st_row = tid >> 3, st_c8 = tid & 7;
  const ushort_t* kgp = Kb + (size_t)(bh * 2048 + st_row) * 64 + st_c8 * 8;
  const ushort_t* vgp = VT + (size_t)(bh * 64 + st_row) * 2048 + st_c8 * 8;
  const int sidx = st_row * 8 + (st_c8 ^ (st_row & 7));

  uint4 kr = *(const uint4*)(kgp);
  uint4 vr = *(const uint4*)(vgp);
  KV[sidx] = kr;
  KV[512 + sidx] = vr;
  __syncthreads();

  f32x16 cacc[2] = {};
  f32x16 lacc = {};

#define ATT_COMPUTE(CB)                                                         \
  {                                                                             \
    f32x16 z = {};                                                              \
    _Pragma("unroll") for (int s = 0; s < 4; ++s) {                             \
      bf16x8 kf = __builtin_bit_cast(bf16x8,                                    \
          KV[(CB) + (half * 32 + ql) * 8 + ((2 * s + h2) ^ (ql & 7))]);         \
      z = __builtin_amdgcn_mfma_f32_32x32x16_bf16(kf, qf[s], z, 0, 0, 0);       \
    }                                                                           \
    bf16x8 pf[2];                                                               \
    _Pragma("unroll") for (int s2 = 0; s2 < 2; ++s2) {                          \
      const int rb = s2 * 8;                                                    \
      float p0 = __builtin_amdgcn_exp2f(z[rb + 0]);                             \
      float p1 = __builtin_amdgcn_exp2f(z[rb + 1]);                             \
      float p2 = __builtin_amdgcn_exp2f(z[rb + 2]);                             \
      float p3 = __builtin_amdgcn_exp2f(z[rb + 3]);                             \
      float p4 = __builtin_amdgcn_exp2f(z[rb + 4]);                             \
      float p5 = __builtin_amdgcn_exp2f(z[rb + 5]);                             \
      float p6 = __builtin_amdgcn_exp2f(z[rb + 6]);                             \
      float p7 = __builtin_amdgcn_exp2f(z[rb + 7]);                             \
      uint32_t a1 = cvt_pk_bf16(p0, p1);                                        \
      uint32_t a2 = cvt_pk_bf16(p2, p3);                                        \
      uint32_t b1 = cvt_pk_bf16(p4, p5);                                        \
      uint32_t b2 = cvt_pk_bf16(p6, p7);                                        \
      permswap(a1, b1);                                                         \
      permswap(a2, b2);                                                         \
      uint4 u = {a1, a2, b1, b2};                                               \
      pf[s2] = __builtin_bit_cast(bf16x8, u);                                   \
    }                                                                           \
    _Pragma("unroll") for (int s2 = 0; s2 < 2; ++s2)                            \
      lacc = __builtin_amdgcn_mfma_f32_32x32x16_bf16(onesf, pf[s2], lacc,       \
                                                     0, 0, 0);                  \
    _Pragma("unroll") for (int dt = 0; dt < 2; ++dt)                            \
      _Pragma("unroll") for (int s2 = 0; s2 < 2; ++s2) {                        \
        const int s = 2 * half + s2;                                            \
        bf16x8 vf = __builtin_bit_cast(bf16x8,                                  \
            KV[(CB) + 512 + (dt * 32 + ql) * 8 + ((2 * s + h2) ^ (ql & 7))]);   \
        cacc[dt] = __builtin_amdgcn_mfma_f32_32x32x16_bf16(vf, pf[s2],          \
                                                           cacc[dt], 0, 0, 0); \
      }                                                                         \
  }

  const ushort_t* kP = kgp + 4096;   // tile 1 (64 rows x 64 elems)
  const ushort_t* vP = vgp + 64;
  for (int tt = 0; tt < 16; ++tt) {
    kr = *(const uint4*)(kP);
    vr = *(const uint4*)(vP);
    ATT_COMPUTE(0)
    KV[1024 + sidx] = kr;
    KV[1536 + sidx] = vr;
    __syncthreads();
    if (tt < 15) {
      kr = *(const uint4*)(kP + 4096);
      vr = *(const uint4*)(vP + 64);
    }
    ATT_COMPUTE(1024)
    if (tt < 15) {
      KV[sidx] = kr;
      KV[512 + sidx] = vr;
      __syncthreads();
    }
    kP += 8192;
    vP += 128;
  }
#undef ATT_COMPUTE

  float lsum = lacc[0];

  __syncthreads();
  float* Lf = (float*)KV;
  const int slot = qw * 64 + lane;          // 0..255
  if (half == 1) {
#pragma unroll
    for (int dt = 0; dt < 2; ++dt)
#pragma unroll
      for (int r = 0; r < 16; ++r)
        Lf[slot * 32 + ((dt * 16 + r) ^ (lane & 31))] = cacc[dt][r];
    Ls[slot] = lsum;
  }
  __syncthreads();
  if (half == 0) {
#pragma unroll
    for (int dt = 0; dt < 2; ++dt)
#pragma unroll
      for (int r = 0; r < 16; ++r)
        cacc[dt][r] += Lf[slot * 32 + ((dt * 16 + r) ^ (lane & 31))];
    lsum += Ls[slot];

    const float rinv = 1.0f / lsum;
    const int b = bh >> 4, h = bh & 15;
    ushort_t* cp = ctx + ((size_t)(b * 2048 + qrow)) * 1024 + h * 64 + h2 * 4;
#pragma unroll
    for (int dt = 0; dt < 2; ++dt)
#pragma unroll
      for (int t = 0; t < 4; ++t) {
        uint2 w;
        w.x = cvt_pk_bf16(cacc[dt][4 * t + 0] * rinv, cacc[dt][4 * t + 1] * rinv);
        w.y = cvt_pk_bf16(cacc[dt][4 * t + 2] * rinv, cacc[dt][4 * t + 3] * rinv);
        *(uint2*)(cp + dt * 32 + t * 8) = w;   // hd = 32dt + 8t + 4h2 + 0..3
      }
  }
}

// ---------------- LayerNorm over rows of 1024 (bf16 in, fp32 out) ------------
__global__ __launch_bounds__(256) void ln_kernel(const ushort_t* __restrict__ x,
    const float* __restrict__ w, const float* __restrict__ b2, float* __restrict__ out)
{
  const int row = blockIdx.x, tid = threadIdx.x;
  const uint2 u = ((const uint2*)(x + (size_t)row * 1024))[tid];   // 4 bf16
  float v0 = b2f((ushort_t)(u.x & 0xFFFF));
  float v1 = b2f((ushort_t)(u.x >> 16));
  float v2 = b2f((ushort_t)(u.y & 0xFFFF));
  float v3 = b2f((ushort_t)(u.y >> 16));
  float s = (v0 + v1) + (v2 + v3);
  float ss = (v0 * v0 + v1 * v1) + (v2 * v2 + v3 * v3);
#pragma unroll
  for (int off = 32; off > 0; off >>= 1) {
    s += __shfl_down(s, off, 64);
    ss += __shfl_down(ss, off, 64);
  }
  __shared__ float red[8];
  if ((tid & 63) == 0) { red[tid >> 6] = s; red[4 + (tid >> 6)] = ss; }
  __syncthreads();
  const float S = red[0] + red[1] + red[2] + red[3];
  const float SS = red[4] + red[5] + red[6] + red[7];
  const float mu = S * (1.f / 1024.f);
  const float rstd = rsqrtf(SS * (1.f / 1024.f) - mu * mu + 1e-12f);
  const int c = tid * 4;
  float4 o;
  o.x = (v0 - mu) * rstd * w[c + 0] + b2[c + 0];
  o.y = (v1 - mu) * rstd * w[c + 1] + b2[c + 1];
  o.z = (v2 - mu) * rstd * w[c + 2] + b2[c + 2];
  o.w = (v3 - mu) * rstd * w[c + 3] + b2[c + 3];
  ((float4*)(out + (size_t)row * 1024))[tid] = o;
}

// ---------------- launch ----------------
extern "C" void kernel_launch(void* const* d_in, const int* in_sizes, int n_in,
                              void* d_out, int out_size, void* d_ws, size_t ws_size,
                              hipStream_t stream) {
  const float* hidden = (const float*)d_in[0];
  const float* cosT = (const float*)d_in[1];
  const float* sinT = (const float*)d_in[2];
  const float* Wq = (const float*)d_in[3];
  const float* bq = (const float*)d_in[4];
  const float* Wk = (const float*)d_in[5];
  const float* bk = (const float*)d_in[6];
  const float* Wv = (const float*)d_in[7];
  const float* bv = (const float*)d_in[8];
  const float* Wo = (const float*)d_in[9];
  const float* bo = (const float*)d_in[10];
  const float* lnw = (const float*)d_in[11];
  const float* lnb = (const float*)d_in[12];

  char* ws = (char*)d_ws;
  const size_t MB = 1u << 20;
  ushort_t* hid_bf = (ushort_t*)(ws);
  ushort_t* wq_bf = (ushort_t*)(ws + 8 * MB);
  ushort_t* wk_bf = (ushort_t*)(ws + 10 * MB);
  ushort_t* wv_bf = (ushort_t*)(ws + 12 * MB);
  ushort_t* wo_bf = (ushort_t*)(ws + 14 * MB);
  ushort_t* q_buf = (ushort_t*)(ws + 16 * MB);
  ushort_t* k_buf = (ushort_t*)(ws + 24 * MB);
  ushort_t* vt_buf = (ushort_t*)(ws + 32 * MB);
  ushort_t* ctx_bf = (ushort_t*)(ws + 40 * MB);
  ushort_t* out_pre = (ushort_t*)(ws + 16 * MB);   // bf16, aliases q (dead)

  cast_all_kernel<<<4096, 256, 0, stream>>>(hidden, Wq, Wk, Wv, Wo,
                                            hid_bf, wq_bf, wk_bf, wv_bf, wo_bf);

  gemm_qkv<<<dim3(32, 8, 3), 256, 0, stream>>>(hid_bf, wq_bf, wk_bf, wv_bf,
                                               bq, bk, bv, cosT, sinT,
                                               q_buf, k_buf, vt_buf);
  attn_kernel<<<512, 512, 0, stream>>>(q_buf, k_buf, vt_buf, ctx_bf);
  gemm_wo<<<dim3(32, 8), 256, 0, stream>>>(ctx_bf, wo_bf, bo, hidden, out_pre);
  ln_kernel<<<4096, 256, 0, stream>>>(out_pre, lnw, lnb, (float*)d_out);
}